// Round 5
// baseline (121.459 us; speedup 1.0000x reference)
//
#include <hip/hip_runtime.h>

// B=D=H=512. Inputs fp32: x, W1, b1, W2, b2, w3, b3.
// d_out = out[512] ++ gram[512,512] (fp32).
// G = 1 + H2H2^T + (1+H1H1^T)⊙(G2G2^T) + (1+XX^T)⊙(G1G1^T)
//   g2 = w3⊙1{z2>0};  g1 = (W2 g2)⊙1{z1>0}
// R5: R4 slimmed. xhi/xlo workspace arrays eliminated:
//   - fwd1 splits x fp32 -> (hi,lo) bf16 IN-REGISTER (identical rounding
//     to the old prep path: hi=f2bf(x), lo=f2bf(x-bf2f(hi))).
//   - XX^T syrk converts x inline -> no prep dependency -> moved into the
//     prep launch as z=2 (runs parallel to the weight transposes).
// Chain: prep(Wt,W2b,XX,out-init) -> fwd1 -> fwd2 -> g1p(G1,P) -> gramf.
// Fixed ~84us of the timed window is harness workspace re-poison
// (2x ~41us fillBuffer, 256MiB each) — not addressable from the kernel.

#define NN 512

typedef __attribute__((ext_vector_type(8))) short v8s;
typedef __attribute__((ext_vector_type(4))) float v4f;

static __device__ __forceinline__ unsigned short f2bf(float f) {
    union { float f; unsigned u; } v; v.f = f;
    unsigned r = v.u + 0x7FFF + ((v.u >> 16) & 1);
    return (unsigned short)(r >> 16);
}
static __device__ __forceinline__ float bf2f(unsigned short h) {
    union { unsigned u; float f; } v; v.u = ((unsigned)h) << 16;
    return v.f;
}

#define MFMA(a, b, c) __builtin_amdgcn_mfma_f32_16x16x32_bf16(a, b, c, 0, 0, 0)

// load 8 consecutive fp32 and round-to-bf16 (hi only)
static __device__ __forceinline__ v8s load8_hi(const float* p) {
    float4 a = *(const float4*)p;
    float4 b = *(const float4*)(p + 4);
    v8s h;
    h[0] = (short)f2bf(a.x); h[1] = (short)f2bf(a.y);
    h[2] = (short)f2bf(a.z); h[3] = (short)f2bf(a.w);
    h[4] = (short)f2bf(b.x); h[5] = (short)f2bf(b.y);
    h[6] = (short)f2bf(b.z); h[7] = (short)f2bf(b.w);
    return h;
}
// load 8 consecutive fp32 and split into (hi, lo) bf16
static __device__ __forceinline__ void load8_split(const float* p, v8s& h, v8s& l) {
    float4 a = *(const float4*)p;
    float4 b = *(const float4*)(p + 4);
    unsigned short h0 = f2bf(a.x), h1 = f2bf(a.y), h2 = f2bf(a.z), h3 = f2bf(a.w);
    unsigned short h4 = f2bf(b.x), h5 = f2bf(b.y), h6 = f2bf(b.z), h7 = f2bf(b.w);
    h[0] = (short)h0; h[1] = (short)h1; h[2] = (short)h2; h[3] = (short)h3;
    h[4] = (short)h4; h[5] = (short)h5; h[6] = (short)h6; h[7] = (short)h7;
    l[0] = (short)f2bf(a.x - bf2f(h0)); l[1] = (short)f2bf(a.y - bf2f(h1));
    l[2] = (short)f2bf(a.z - bf2f(h2)); l[3] = (short)f2bf(a.w - bf2f(h3));
    l[4] = (short)f2bf(b.x - bf2f(h4)); l[5] = (short)f2bf(b.y - bf2f(h5));
    l[6] = (short)f2bf(b.z - bf2f(h6)); l[7] = (short)f2bf(b.w - bf2f(h7));
}

// ---- prep: z=0: W1 transpose+split; z=1: W2 transpose+split + plain W2b;
//            z=2: SXX = XX^T syrk (inline bf16 convert) + out[i]=b3 --------
__global__ __launch_bounds__(256) void prep(
    const float* __restrict__ x, const float* __restrict__ W1,
    const float* __restrict__ W2, const float* __restrict__ b3,
    unsigned short* __restrict__ W1th, unsigned short* __restrict__ W1tl,
    unsigned short* __restrict__ W2th, unsigned short* __restrict__ W2tl,
    unsigned short* __restrict__ W2b, float* __restrict__ SXX,
    float* __restrict__ out) {
    __shared__ float T[32][33];
    const int t = threadIdx.x;
    const int r0 = blockIdx.y * 32, c0 = blockIdx.x * 32;
    const int z = blockIdx.z;
    if (z == 2) {
        // XX^T syrk: 4 waves, one 16x16 quadrant each, full K=512.
        const int wave = t >> 6, lane = t & 63;
        const int r = lane & 15, quad = lane >> 4;
        const int i0 = r0 + 16 * (wave >> 1);
        const int j0 = c0 + 16 * (wave & 1);
        const float* ar = x + (i0 + r) * NN + quad * 8;
        const float* br = x + (j0 + r) * NN + quad * 8;
        v4f acc = {0.f, 0.f, 0.f, 0.f};
        #pragma unroll
        for (int k0 = 0; k0 < NN; k0 += 32) {
            v8s a = load8_hi(ar + k0);
            v8s b = load8_hi(br + k0);
            acc = MFMA(a, b, acc);
        }
        #pragma unroll
        for (int rr = 0; rr < 4; ++rr)
            SXX[(i0 + quad * 4 + rr) * NN + j0 + r] = acc[rr];
        if (blockIdx.x == 0 && t < 32) out[r0 + t] = b3[0];
        return;
    }
    const int lr = t >> 3, lc = (t & 7) * 4;
    const float* src = (z == 1) ? W2 : W1;
    float4 v = *(const float4*)&src[(r0 + lr) * NN + c0 + lc];
    if (z == 1) {
        ushort4 h;
        h.x = f2bf(v.x); h.y = f2bf(v.y); h.z = f2bf(v.z); h.w = f2bf(v.w);
        *(ushort4*)&W2b[(r0 + lr) * NN + c0 + lc] = h;
    }
    T[lr][lc + 0] = v.x; T[lr][lc + 1] = v.y;
    T[lr][lc + 2] = v.z; T[lr][lc + 3] = v.w;
    __syncthreads();
    unsigned short* dh = (z == 1) ? W2th : W1th;
    unsigned short* dl = (z == 1) ? W2tl : W1tl;
    float a0 = T[lc + 0][lr], a1 = T[lc + 1][lr];
    float a2 = T[lc + 2][lr], a3 = T[lc + 3][lr];
    ushort4 hi, lo;
    hi.x = f2bf(a0); lo.x = f2bf(a0 - bf2f(hi.x));
    hi.y = f2bf(a1); lo.y = f2bf(a1 - bf2f(hi.y));
    hi.z = f2bf(a2); lo.z = f2bf(a2 - bf2f(hi.z));
    hi.w = f2bf(a3); lo.w = f2bf(a3 - bf2f(hi.w));
    *(ushort4*)&dh[(c0 + lr) * NN + r0 + lc] = hi;
    *(ushort4*)&dl[(c0 + lr) * NN + r0 + lc] = lo;
}

// ---- fwd1: h1 = relu(x@W1+b1), x split in-register; split-K x4 -----------
__global__ __launch_bounds__(1024, 4) void fwd1(
    const float* __restrict__ x,
    const unsigned short* __restrict__ Bhi, const unsigned short* __restrict__ Blo,
    const float* __restrict__ bias,
    unsigned short* __restrict__ Chi, unsigned short* __restrict__ Clo) {
    __shared__ float red[12][64][4];
    const int t = threadIdx.x;
    const int wave = t >> 6, lane = t & 63;
    const int q = wave & 3, s = wave >> 2;
    const int r = lane & 15, quad = lane >> 4;
    const int i0 = blockIdx.y * 32 + 16 * (q >> 1);
    const int j0 = blockIdx.x * 32 + 16 * (q & 1);
    const float* ar = x + (i0 + r) * NN + quad * 8 + s * 128;
    const int bo = (j0 + r) * NN + quad * 8 + s * 128;
    v4f hh = {0.f, 0.f, 0.f, 0.f}, lh = hh, hl = hh;
    #pragma unroll
    for (int k0 = 0; k0 < 128; k0 += 32) {
        v8s ah, al;
        load8_split(ar + k0, ah, al);
        v8s bh = *(const v8s*)(Bhi + bo + k0);
        v8s bl = *(const v8s*)(Blo + bo + k0);
        hh = MFMA(ah, bh, hh);
        lh = MFMA(al, bh, lh);
        hl = MFMA(ah, bl, hl);
    }
    v4f z;
    #pragma unroll
    for (int rr = 0; rr < 4; ++rr) z[rr] = (hh[rr] + lh[rr]) + hl[rr];
    if (s > 0) *(v4f*)red[(s - 1) * 4 + q][lane] = z;
    __syncthreads();
    if (s == 0) {
        v4f z0 = z + *(v4f*)red[q][lane] + *(v4f*)red[4 + q][lane]
                   + *(v4f*)red[8 + q][lane];
        const float bj = bias[j0 + r];
        #pragma unroll
        for (int rr = 0; rr < 4; ++rr) {
            const int i = i0 + quad * 4 + rr, j = j0 + r;
            float zv = z0[rr] + bj;
            float h = zv > 0.f ? zv : 0.f;
            unsigned short hi = f2bf(h);
            Chi[i * NN + j] = hi;
            Clo[i * NN + j] = f2bf(h - bf2f(hi));
        }
    }
}

// ---- fwd2: z2 = H1@W2+b2; writes H2b, G2b, out += h2.w3 ------------------
__global__ __launch_bounds__(1024, 4) void fwd2(
    const unsigned short* __restrict__ Ahi, const unsigned short* __restrict__ Alo,
    const unsigned short* __restrict__ Bhi, const unsigned short* __restrict__ Blo,
    const float* __restrict__ b2, const float* __restrict__ w3,
    unsigned short* __restrict__ H2b, unsigned short* __restrict__ G2b,
    float* __restrict__ out) {
    __shared__ float red[12][64][4];
    const int t = threadIdx.x;
    const int wave = t >> 6, lane = t & 63;
    const int q = wave & 3, s = wave >> 2;
    const int r = lane & 15, quad = lane >> 4;
    const int i0 = blockIdx.y * 32 + 16 * (q >> 1);
    const int j0 = blockIdx.x * 32 + 16 * (q & 1);
    const int ao = (i0 + r) * NN + quad * 8 + s * 128;
    const int bo = (j0 + r) * NN + quad * 8 + s * 128;
    v4f hh = {0.f, 0.f, 0.f, 0.f}, lh = hh, hl = hh;
    #pragma unroll
    for (int k0 = 0; k0 < 128; k0 += 32) {
        v8s ah = *(const v8s*)(Ahi + ao + k0);
        v8s al = *(const v8s*)(Alo + ao + k0);
        v8s bh = *(const v8s*)(Bhi + bo + k0);
        v8s bl = *(const v8s*)(Blo + bo + k0);
        hh = MFMA(ah, bh, hh);
        lh = MFMA(al, bh, lh);
        hl = MFMA(ah, bl, hl);
    }
    v4f z;
    #pragma unroll
    for (int rr = 0; rr < 4; ++rr) z[rr] = (hh[rr] + lh[rr]) + hl[rr];
    if (s > 0) *(v4f*)red[(s - 1) * 4 + q][lane] = z;
    __syncthreads();
    if (s == 0) {
        v4f z0 = z + *(v4f*)red[q][lane] + *(v4f*)red[4 + q][lane]
                   + *(v4f*)red[8 + q][lane];
        const float bj = b2[j0 + r];
        const float wj = w3[j0 + r];
        const unsigned short wjb = f2bf(wj);
        #pragma unroll
        for (int rr = 0; rr < 4; ++rr) {
            const int i = i0 + quad * 4 + rr, j = j0 + r;
            float zv = z0[rr] + bj;
            float h = zv > 0.f ? zv : 0.f;
            H2b[i * NN + j] = f2bf(h);
            G2b[i * NN + j] = (zv > 0.f) ? wjb : (unsigned short)0;
            float p = h * wj;
            p += __shfl_xor(p, 1, 64);
            p += __shfl_xor(p, 2, 64);
            p += __shfl_xor(p, 4, 64);
            p += __shfl_xor(p, 8, 64);
            if (r == 0) atomicAdd(&out[i], p);
        }
    }
}

// ---- g1p: z=0: G1 = 1{H1>0}.(G2@W2^T); z=1: P = H2H2+G2G2.(1+H1H1) ------
__global__ __launch_bounds__(1024, 4) void g1p(
    const unsigned short* __restrict__ G2b, const unsigned short* __restrict__ W2b,
    const unsigned short* __restrict__ H1b, const unsigned short* __restrict__ H2b,
    unsigned short* __restrict__ G1b, float* __restrict__ P) {
    __shared__ float red[12][64][3][4];
    const int t = threadIdx.x;
    const int wave = t >> 6, lane = t & 63;
    const int q = wave & 3, s = wave >> 2;
    const int r = lane & 15, quad = lane >> 4;
    const int i0 = blockIdx.y * 32 + 16 * (q >> 1);
    const int j0 = blockIdx.x * 32 + 16 * (q & 1);
    const int ao = (i0 + r) * NN + quad * 8 + s * 128;
    const int bo = (j0 + r) * NN + quad * 8 + s * 128;
    if (blockIdx.z == 1) {
        v4f a1 = {0.f, 0.f, 0.f, 0.f}, a3 = a1, a4 = a1;
        #pragma unroll
        for (int k0 = 0; k0 < 128; k0 += 32) {
            v8s ha = *(const v8s*)(H1b + ao + k0), hb = *(const v8s*)(H1b + bo + k0);
            v8s ua = *(const v8s*)(H2b + ao + k0), ub = *(const v8s*)(H2b + bo + k0);
            v8s va = *(const v8s*)(G2b + ao + k0), vb = *(const v8s*)(G2b + bo + k0);
            a1 = MFMA(ha, hb, a1);
            a3 = MFMA(ua, ub, a3);
            a4 = MFMA(va, vb, a4);
        }
        if (s > 0) {
            const int idx = (s - 1) * 4 + q;
            *(v4f*)red[idx][lane][0] = a1;
            *(v4f*)red[idx][lane][1] = a3;
            *(v4f*)red[idx][lane][2] = a4;
        }
        __syncthreads();
        if (s == 0) {
            #pragma unroll
            for (int u = 0; u < 3; ++u) {
                const int idx = u * 4 + q;
                a1 += *(v4f*)red[idx][lane][0];
                a3 += *(v4f*)red[idx][lane][1];
                a4 += *(v4f*)red[idx][lane][2];
            }
            #pragma unroll
            for (int rr = 0; rr < 4; ++rr) {
                const int i = i0 + quad * 4 + rr, j = j0 + r;
                P[i * NN + j] = a3[rr] + a4[rr] * (1.f + a1[rr]);
            }
        }
        return;
    }
    v4f acc = {0.f, 0.f, 0.f, 0.f};
    #pragma unroll
    for (int k0 = 0; k0 < 128; k0 += 32) {
        v8s a = *(const v8s*)(G2b + ao + k0);
        v8s b = *(const v8s*)(W2b + bo + k0);
        acc = MFMA(a, b, acc);
    }
    if (s > 0) *(v4f*)red[(s - 1) * 4 + q][lane][0] = acc;
    __syncthreads();
    if (s == 0) {
        v4f a0 = acc + *(v4f*)red[q][lane][0] + *(v4f*)red[4 + q][lane][0]
                     + *(v4f*)red[8 + q][lane][0];
        #pragma unroll
        for (int rr = 0; rr < 4; ++rr) {
            const int i = i0 + quad * 4 + rr;
            const int c = j0 + r;
            // h1 >= 0, bf16(h1) != 0 iff h1 > 0 (up to denormal cutoff)
            float v = (H1b[i * NN + c] != 0) ? a0[rr] : 0.f;
            G1b[i * NN + c] = f2bf(v);
        }
    }
}

// ---- gramf: G1 syrk + combine with precomputed SXX, P --------------------
__global__ __launch_bounds__(1024, 4) void gramf(
    const unsigned short* __restrict__ G1b, const float* __restrict__ SXX,
    const float* __restrict__ P, float* __restrict__ gram) {
    __shared__ float red[12][64][4];
    const int t = threadIdx.x;
    const int wave = t >> 6, lane = t & 63;
    const int q = wave & 3, s = wave >> 2;
    const int r = lane & 15, quad = lane >> 4;
    const int i0 = blockIdx.y * 32 + 16 * (q >> 1);
    const int j0 = blockIdx.x * 32 + 16 * (q & 1);
    const int ao = (i0 + r) * NN + quad * 8 + s * 128;
    const int bo = (j0 + r) * NN + quad * 8 + s * 128;
    v4f acc = {0.f, 0.f, 0.f, 0.f};
    #pragma unroll
    for (int k0 = 0; k0 < 128; k0 += 32) {
        v8s a = *(const v8s*)(G1b + ao + k0);
        v8s b = *(const v8s*)(G1b + bo + k0);
        acc = MFMA(a, b, acc);
    }
    if (s > 0) *(v4f*)red[(s - 1) * 4 + q][lane] = acc;
    __syncthreads();
    if (s == 0) {
        v4f a2 = acc + *(v4f*)red[q][lane] + *(v4f*)red[4 + q][lane]
                     + *(v4f*)red[8 + q][lane];
        #pragma unroll
        for (int rr = 0; rr < 4; ++rr) {
            const int i = i0 + quad * 4 + rr, j = j0 + r;
            gram[i * NN + j] = 1.f + P[i * NN + j] + a2[rr] * (1.f + SXX[i * NN + j]);
        }
    }
}

extern "C" void kernel_launch(void* const* d_in, const int* in_sizes, int n_in,
                              void* d_out, int out_size, void* d_ws, size_t ws_size,
                              hipStream_t stream) {
    const float* x  = (const float*)d_in[0];
    const float* W1 = (const float*)d_in[1];
    const float* b1 = (const float*)d_in[2];
    const float* W2 = (const float*)d_in[3];
    const float* b2 = (const float*)d_in[4];
    const float* w3 = (const float*)d_in[5];
    const float* b3 = (const float*)d_in[6];

    float* out  = (float*)d_out;
    float* gram = out + NN;

    // 10 bf16 [512][512] arrays (512 KB) + 2 fp32 [512][512] (1 MB)
    unsigned short* p    = (unsigned short*)d_ws;
    unsigned short* W1th = p;  p += NN * NN;
    unsigned short* W1tl = p;  p += NN * NN;
    unsigned short* W2th = p;  p += NN * NN;
    unsigned short* W2tl = p;  p += NN * NN;
    unsigned short* W2b  = p;  p += NN * NN;
    unsigned short* H1b  = p;  p += NN * NN;
    unsigned short* H1lo = p;  p += NN * NN;
    unsigned short* H2b  = p;  p += NN * NN;
    unsigned short* G2b  = p;  p += NN * NN;
    unsigned short* G1b  = p;  p += NN * NN;
    float* SXX = (float*)p;  p += 2 * NN * NN;
    float* Pf  = (float*)p;  p += 2 * NN * NN;

    prep <<<dim3(16, 16, 3), dim3(256), 0, stream>>>(
        x, W1, W2, b3, W1th, W1tl, W2th, W2tl, W2b, SXX, out);
    fwd1 <<<dim3(16, 16), dim3(1024), 0, stream>>>(
        x, W1th, W1tl, b1, H1b, H1lo);
    fwd2 <<<dim3(16, 16), dim3(1024), 0, stream>>>(
        H1b, H1lo, W2th, W2tl, b2, w3, H2b, G2b, out);
    g1p  <<<dim3(16, 16, 2), dim3(1024), 0, stream>>>(
        G2b, W2b, H1b, H2b, G1b, Pf);
    gramf<<<dim3(16, 16), dim3(1024), 0, stream>>>(
        G1b, SXX, Pf, gram);
}

// Round 6
// 114.679 us; speedup vs baseline: 1.0591x; 1.0591x over previous
//
#include <hip/hip_runtime.h>

// B=D=H=512. Inputs fp32: x, W1, b1, W2, b2, w3, b3.
// d_out = out[512] ++ gram[512,512] (fp32).
// G = 1 + H2H2^T + (1+H1H1^T)⊙(G2G2^T) + (1+XX^T)⊙(G1G1^T)
//   g2 = w3⊙1{z2>0};  g1 = (W2 g2)⊙1{z1>0}
// R6 = best-known per-kernel shape (256-thr full-K waves, prev-session 114.7)
//      + R4's work placement (SXX syrk as fwd1 z-slice, P syrk as g1p
//      z-slice, slim 1-syrk tail).
// Ledger: 2x ~41.5us workspace re-poison fills = 83us fixed in the timed
// window (L2+L3 flushed every iteration -> chain kernels are L3-latency
// bound). Controllable chain ~30us. Launch gaps ~1us (R3 decomposition).
// Lessons: inline fp32->bf16 in GEMM loops is 16x-replicated (R5, -5.6us);
// grid.sync flushes L2 (R1, -123us); row-fusion caps blocks at 32 (R3).

#define NN 512

typedef __attribute__((ext_vector_type(8))) short v8s;
typedef __attribute__((ext_vector_type(4))) float v4f;

static __device__ __forceinline__ unsigned short f2bf(float f) {
    union { float f; unsigned u; } v; v.f = f;
    unsigned r = v.u + 0x7FFF + ((v.u >> 16) & 1);
    return (unsigned short)(r >> 16);
}
static __device__ __forceinline__ float bf2f(unsigned short h) {
    union { unsigned u; float f; } v; v.u = ((unsigned)h) << 16;
    return v.f;
}

#define MFMA(a, b, c) __builtin_amdgcn_mfma_f32_16x16x32_bf16(a, b, c, 0, 0, 0)

// ---- prep: z=0: W1 transpose+split; z=1: W2 transpose+split + plain W2b;
//            z=2: x straight split + out[i]=b3 ------------------------------
__global__ __launch_bounds__(256) void prep(
    const float* __restrict__ x, const float* __restrict__ W1,
    const float* __restrict__ W2, const float* __restrict__ b3,
    unsigned short* __restrict__ xhi, unsigned short* __restrict__ xlo,
    unsigned short* __restrict__ W1th, unsigned short* __restrict__ W1tl,
    unsigned short* __restrict__ W2th, unsigned short* __restrict__ W2tl,
    unsigned short* __restrict__ W2b, float* __restrict__ out) {
    __shared__ float T[32][33];
    const int t = threadIdx.x;
    const int lr = t >> 3, lc = (t & 7) * 4;
    const int r0 = blockIdx.y * 32, c0 = blockIdx.x * 32;
    const int z = blockIdx.z;
    if (z == 2) {
        float4 v = *(const float4*)&x[(r0 + lr) * NN + c0 + lc];
        ushort4 hi, lo;
        hi.x = f2bf(v.x); lo.x = f2bf(v.x - bf2f(hi.x));
        hi.y = f2bf(v.y); lo.y = f2bf(v.y - bf2f(hi.y));
        hi.z = f2bf(v.z); lo.z = f2bf(v.z - bf2f(hi.z));
        hi.w = f2bf(v.w); lo.w = f2bf(v.w - bf2f(hi.w));
        *(ushort4*)&xhi[(r0 + lr) * NN + c0 + lc] = hi;
        *(ushort4*)&xlo[(r0 + lr) * NN + c0 + lc] = lo;
        if (blockIdx.x == 0 && t < 32) out[r0 + t] = b3[0];
        return;
    }
    const float* src = (z == 1) ? W2 : W1;
    float4 v = *(const float4*)&src[(r0 + lr) * NN + c0 + lc];
    if (z == 1) {
        ushort4 h;
        h.x = f2bf(v.x); h.y = f2bf(v.y); h.z = f2bf(v.z); h.w = f2bf(v.w);
        *(ushort4*)&W2b[(r0 + lr) * NN + c0 + lc] = h;
    }
    T[lr][lc + 0] = v.x; T[lr][lc + 1] = v.y;
    T[lr][lc + 2] = v.z; T[lr][lc + 3] = v.w;
    __syncthreads();
    unsigned short* dh = (z == 1) ? W2th : W1th;
    unsigned short* dl = (z == 1) ? W2tl : W1tl;
    float a0 = T[lc + 0][lr], a1 = T[lc + 1][lr];
    float a2 = T[lc + 2][lr], a3 = T[lc + 3][lr];
    ushort4 hi, lo;
    hi.x = f2bf(a0); lo.x = f2bf(a0 - bf2f(hi.x));
    hi.y = f2bf(a1); lo.y = f2bf(a1 - bf2f(hi.y));
    hi.z = f2bf(a2); lo.z = f2bf(a2 - bf2f(hi.z));
    hi.w = f2bf(a3); lo.w = f2bf(a3 - bf2f(hi.w));
    *(ushort4*)&dh[(c0 + lr) * NN + r0 + lc] = hi;
    *(ushort4*)&dl[(c0 + lr) * NN + r0 + lc] = lo;
}

// ---- fwd1x: z=0: h1 = relu(x@W1+b1) split out; z=1: SXX = XX^T syrk ------
__global__ __launch_bounds__(256) void fwd1x(
    const unsigned short* __restrict__ Ahi, const unsigned short* __restrict__ Alo,
    const unsigned short* __restrict__ Bhi, const unsigned short* __restrict__ Blo,
    const float* __restrict__ bias,
    unsigned short* __restrict__ Chi, unsigned short* __restrict__ Clo,
    float* __restrict__ SXX) {
    const int t = threadIdx.x;
    const int wave = t >> 6, lane = t & 63;
    const int r = lane & 15, quad = lane >> 4;
    const int i0 = blockIdx.y * 32 + 16 * (wave >> 1);
    const int j0 = blockIdx.x * 32 + 16 * (wave & 1);
    const int ao = (i0 + r) * NN + quad * 8;
    const int bo = (j0 + r) * NN + quad * 8;
    if (blockIdx.z == 1) {
        // XX^T syrk on hi parts (same operand precision as the 5-syrk gramk)
        v4f acc = {0.f, 0.f, 0.f, 0.f};
        #pragma unroll
        for (int k0 = 0; k0 < NN; k0 += 32) {
            v8s a = *(const v8s*)(Ahi + ao + k0);
            v8s b = *(const v8s*)(Ahi + bo + k0);
            acc = MFMA(a, b, acc);
        }
        #pragma unroll
        for (int rr = 0; rr < 4; ++rr)
            SXX[(i0 + quad * 4 + rr) * NN + j0 + r] = acc[rr];
        return;
    }
    v4f hh = {0.f, 0.f, 0.f, 0.f}, lh = hh, hl = hh;
    #pragma unroll
    for (int k0 = 0; k0 < NN; k0 += 32) {
        v8s ah = *(const v8s*)(Ahi + ao + k0);
        v8s al = *(const v8s*)(Alo + ao + k0);
        v8s bh = *(const v8s*)(Bhi + bo + k0);
        v8s bl = *(const v8s*)(Blo + bo + k0);
        hh = MFMA(ah, bh, hh);
        lh = MFMA(al, bh, lh);
        hl = MFMA(ah, bl, hl);
    }
    const float bj = bias[j0 + r];
    #pragma unroll
    for (int rr = 0; rr < 4; ++rr) {
        const int i = i0 + quad * 4 + rr, j = j0 + r;
        float zv = (hh[rr] + lh[rr]) + hl[rr] + bj;
        float h = zv > 0.f ? zv : 0.f;
        unsigned short hi = f2bf(h);
        Chi[i * NN + j] = hi;
        Clo[i * NN + j] = f2bf(h - bf2f(hi));
    }
}

// ---- fwd2: z2 = H1@W2+b2; writes H2b, G2b, out += h2.w3 ------------------
__global__ __launch_bounds__(256) void fwd2(
    const unsigned short* __restrict__ Ahi, const unsigned short* __restrict__ Alo,
    const unsigned short* __restrict__ Bhi, const unsigned short* __restrict__ Blo,
    const float* __restrict__ b2, const float* __restrict__ w3,
    unsigned short* __restrict__ H2b, unsigned short* __restrict__ G2b,
    float* __restrict__ out) {
    const int t = threadIdx.x;
    const int wave = t >> 6, lane = t & 63;
    const int r = lane & 15, quad = lane >> 4;
    const int i0 = blockIdx.y * 32 + 16 * (wave >> 1);
    const int j0 = blockIdx.x * 32 + 16 * (wave & 1);
    const int ao = (i0 + r) * NN + quad * 8;
    const int bo = (j0 + r) * NN + quad * 8;
    v4f hh = {0.f, 0.f, 0.f, 0.f}, lh = hh, hl = hh;
    #pragma unroll
    for (int k0 = 0; k0 < NN; k0 += 32) {
        v8s ah = *(const v8s*)(Ahi + ao + k0);
        v8s al = *(const v8s*)(Alo + ao + k0);
        v8s bh = *(const v8s*)(Bhi + bo + k0);
        v8s bl = *(const v8s*)(Blo + bo + k0);
        hh = MFMA(ah, bh, hh);
        lh = MFMA(al, bh, lh);
        hl = MFMA(ah, bl, hl);
    }
    const float bj = b2[j0 + r];
    const float wj = w3[j0 + r];
    const unsigned short wjb = f2bf(wj);
    #pragma unroll
    for (int rr = 0; rr < 4; ++rr) {
        const int i = i0 + quad * 4 + rr, j = j0 + r;
        float zv = (hh[rr] + lh[rr]) + hl[rr] + bj;
        float h = zv > 0.f ? zv : 0.f;
        H2b[i * NN + j] = f2bf(h);
        G2b[i * NN + j] = (zv > 0.f) ? wjb : (unsigned short)0;
        float p = h * wj;
        p += __shfl_xor(p, 1, 64);
        p += __shfl_xor(p, 2, 64);
        p += __shfl_xor(p, 4, 64);
        p += __shfl_xor(p, 8, 64);
        if (r == 0) atomicAdd(&out[i], p);
    }
}

// ---- g1p: z=0: G1 = 1{H1>0}.(G2@W2^T); z=1: P = H2H2+G2G2.(1+H1H1) ------
__global__ __launch_bounds__(256) void g1p(
    const unsigned short* __restrict__ G2b, const unsigned short* __restrict__ W2b,
    const unsigned short* __restrict__ H1b, const unsigned short* __restrict__ H2b,
    unsigned short* __restrict__ G1b, float* __restrict__ P) {
    const int t = threadIdx.x;
    const int wave = t >> 6, lane = t & 63;
    const int r = lane & 15, quad = lane >> 4;
    const int i0 = blockIdx.y * 32 + 16 * (wave >> 1);
    const int j0 = blockIdx.x * 32 + 16 * (wave & 1);
    const int ao = (i0 + r) * NN + quad * 8;
    const int bo = (j0 + r) * NN + quad * 8;
    if (blockIdx.z == 1) {
        v4f a1 = {0.f, 0.f, 0.f, 0.f}, a3 = a1, a4 = a1;
        #pragma unroll
        for (int k0 = 0; k0 < NN; k0 += 32) {
            v8s ha = *(const v8s*)(H1b + ao + k0), hb = *(const v8s*)(H1b + bo + k0);
            v8s ua = *(const v8s*)(H2b + ao + k0), ub = *(const v8s*)(H2b + bo + k0);
            v8s va = *(const v8s*)(G2b + ao + k0), vb = *(const v8s*)(G2b + bo + k0);
            a1 = MFMA(ha, hb, a1);
            a3 = MFMA(ua, ub, a3);
            a4 = MFMA(va, vb, a4);
        }
        #pragma unroll
        for (int rr = 0; rr < 4; ++rr) {
            const int i = i0 + quad * 4 + rr, j = j0 + r;
            P[i * NN + j] = a3[rr] + a4[rr] * (1.f + a1[rr]);
        }
        return;
    }
    v4f acc = {0.f, 0.f, 0.f, 0.f};
    #pragma unroll
    for (int k0 = 0; k0 < NN; k0 += 32) {
        v8s a = *(const v8s*)(G2b + ao + k0);
        v8s b = *(const v8s*)(W2b + bo + k0);
        acc = MFMA(a, b, acc);
    }
    #pragma unroll
    for (int rr = 0; rr < 4; ++rr) {
        const int i = i0 + quad * 4 + rr;
        const int c = j0 + r;
        // h1 >= 0, bf16(h1) != 0 iff h1 > 0 (up to denormal cutoff)
        float v = (H1b[i * NN + c] != 0) ? acc[rr] : 0.f;
        G1b[i * NN + c] = f2bf(v);
    }
}

// ---- gramf: G1 syrk + combine with precomputed SXX, P --------------------
__global__ __launch_bounds__(256) void gramf(
    const unsigned short* __restrict__ G1b, const float* __restrict__ SXX,
    const float* __restrict__ P, float* __restrict__ gram) {
    const int t = threadIdx.x;
    const int wave = t >> 6, lane = t & 63;
    const int r = lane & 15, quad = lane >> 4;
    const int i0 = blockIdx.y * 32 + 16 * (wave >> 1);
    const int j0 = blockIdx.x * 32 + 16 * (wave & 1);
    const int ao = (i0 + r) * NN + quad * 8;
    const int bo = (j0 + r) * NN + quad * 8;
    // hoist epilogue loads above the K-loop (overlap with syrk latency)
    float sx[4], pp[4];
    #pragma unroll
    for (int rr = 0; rr < 4; ++rr) {
        const int i = i0 + quad * 4 + rr, j = j0 + r;
        sx[rr] = SXX[i * NN + j];
        pp[rr] = P[i * NN + j];
    }
    v4f acc = {0.f, 0.f, 0.f, 0.f};
    #pragma unroll
    for (int k0 = 0; k0 < NN; k0 += 32) {
        v8s a = *(const v8s*)(G1b + ao + k0);
        v8s b = *(const v8s*)(G1b + bo + k0);
        acc = MFMA(a, b, acc);
    }
    #pragma unroll
    for (int rr = 0; rr < 4; ++rr) {
        const int i = i0 + quad * 4 + rr, j = j0 + r;
        gram[i * NN + j] = 1.f + pp[rr] + acc[rr] * (1.f + sx[rr]);
    }
}

extern "C" void kernel_launch(void* const* d_in, const int* in_sizes, int n_in,
                              void* d_out, int out_size, void* d_ws, size_t ws_size,
                              hipStream_t stream) {
    const float* x  = (const float*)d_in[0];
    const float* W1 = (const float*)d_in[1];
    const float* b1 = (const float*)d_in[2];
    const float* W2 = (const float*)d_in[3];
    const float* b2 = (const float*)d_in[4];
    const float* w3 = (const float*)d_in[5];
    const float* b3 = (const float*)d_in[6];

    float* out  = (float*)d_out;
    float* gram = out + NN;

    // 12 bf16 [512][512] arrays (512 KB) + 2 fp32 [512][512] (1 MB)
    unsigned short* p    = (unsigned short*)d_ws;
    unsigned short* xhi  = p;  p += NN * NN;
    unsigned short* xlo  = p;  p += NN * NN;
    unsigned short* W1th = p;  p += NN * NN;
    unsigned short* W1tl = p;  p += NN * NN;
    unsigned short* W2th = p;  p += NN * NN;
    unsigned short* W2tl = p;  p += NN * NN;
    unsigned short* W2b  = p;  p += NN * NN;
    unsigned short* H1b  = p;  p += NN * NN;
    unsigned short* H1lo = p;  p += NN * NN;
    unsigned short* H2b  = p;  p += NN * NN;
    unsigned short* G2b  = p;  p += NN * NN;
    unsigned short* G1b  = p;  p += NN * NN;
    float* SXX = (float*)p;  p += 2 * NN * NN;
    float* Pf  = (float*)p;  p += 2 * NN * NN;

    dim3 blk(256);
    prep <<<dim3(16, 16, 3), blk, 0, stream>>>(
        x, W1, W2, b3, xhi, xlo, W1th, W1tl, W2th, W2tl, W2b, out);
    fwd1x<<<dim3(16, 16, 2), blk, 0, stream>>>(
        xhi, xlo, W1th, W1tl, b1, H1b, H1lo, SXX);
    fwd2 <<<dim3(16, 16), blk, 0, stream>>>(
        H1b, H1lo, W2th, W2tl, b2, w3, H2b, G2b, out);
    g1p  <<<dim3(16, 16, 2), blk, 0, stream>>>(
        G2b, W2b, H1b, H2b, G1b, Pf);
    gramf<<<dim3(16, 16), blk, 0, stream>>>(
        G1b, SXX, Pf, gram);
}